// Round 1
// baseline (4465.538 us; speedup 1.0000x reference)
//
#include <hip/hip_runtime.h>
#include <stdint.h>

// Problem constants (match reference)
#define M_     4
#define B_     256
#define NPG_   64
#define N_     (B_*NPG_)    // 16384
#define DEG_   8
#define E_     (N_*DEG_)    // 131072
#define DF_    16
#define D_     256
#define L_     5
#define NA_    2
#define TASKS_ 10

#define SA 260   // padded LDS row stride (floats) for 64x256 node buffers

// ---------------- Threefry-2x32 (exact JAX semantics) ----------------
__device__ __forceinline__ uint32_t rotl32(uint32_t v, int r) { return (v << r) | (v >> (32 - r)); }

__device__ __forceinline__ void threefry2x32(uint32_t k0, uint32_t k1, uint32_t x0, uint32_t x1,
                                             uint32_t& o0, uint32_t& o1) {
  const uint32_t ks2 = k0 ^ k1 ^ 0x1BD11BDAu;
  x0 += k0; x1 += k1;
#define TFR(r) { x0 += x1; x1 = rotl32(x1, r); x1 ^= x0; }
  TFR(13) TFR(15) TFR(26) TFR(6)   x0 += k1;  x1 += ks2 + 1u;
  TFR(17) TFR(29) TFR(16) TFR(24)  x0 += ks2; x1 += k0 + 2u;
  TFR(13) TFR(15) TFR(26) TFR(6)   x0 += k0;  x1 += k1 + 3u;
  TFR(17) TFR(29) TFR(16) TFR(24)  x0 += k1;  x1 += ks2 + 4u;
  TFR(13) TFR(15) TFR(26) TFR(6)   x0 += ks2; x1 += k0 + 5u;
#undef TFR
  o0 = x0; o1 = x1;
}

// ---------------- small helper: 8x4 register-tile FMA ----------------
__device__ __forceinline__ void fma_8x4(float (&acc)[8][4], const float4 (&av)[8], const float4 (&wv)[4]) {
#pragma unroll
  for (int ii = 0; ii < 8; ++ii) {
    const float4 a_ = av[ii];
    acc[ii][0] = fmaf(a_.x, wv[0].x, acc[ii][0]);
    acc[ii][1] = fmaf(a_.x, wv[0].y, acc[ii][1]);
    acc[ii][2] = fmaf(a_.x, wv[0].z, acc[ii][2]);
    acc[ii][3] = fmaf(a_.x, wv[0].w, acc[ii][3]);
    acc[ii][0] = fmaf(a_.y, wv[1].x, acc[ii][0]);
    acc[ii][1] = fmaf(a_.y, wv[1].y, acc[ii][1]);
    acc[ii][2] = fmaf(a_.y, wv[1].z, acc[ii][2]);
    acc[ii][3] = fmaf(a_.y, wv[1].w, acc[ii][3]);
    acc[ii][0] = fmaf(a_.z, wv[2].x, acc[ii][0]);
    acc[ii][1] = fmaf(a_.z, wv[2].y, acc[ii][1]);
    acc[ii][2] = fmaf(a_.z, wv[2].z, acc[ii][2]);
    acc[ii][3] = fmaf(a_.z, wv[2].w, acc[ii][3]);
    acc[ii][0] = fmaf(a_.w, wv[3].x, acc[ii][0]);
    acc[ii][1] = fmaf(a_.w, wv[3].y, acc[ii][1]);
    acc[ii][2] = fmaf(a_.w, wv[3].z, acc[ii][2]);
    acc[ii][3] = fmaf(a_.w, wv[3].w, acc[ii][3]);
  }
}

// Out[64][256] = (relu?)(Ain[64][256] @ W[256][256] + bias), all node bufs LDS (stride SA), W global.
// 512 threads: thread tile 8 rows x 4 cols. W staged in 8-row LDS panels.
__device__ __forceinline__ void gemm_w(const float* __restrict__ Ain, float* __restrict__ Out,
                                       const float* __restrict__ W, const float* __restrict__ bias,
                                       float* __restrict__ Wpan, bool do_relu) {
  const int tid = threadIdx.x;
  const int it = tid >> 6;      // 0..7
  const int dt = tid & 63;      // 0..63
  const int i0 = it * 8;
  const int d0 = dt * 4;
  float acc[8][4];
  const float4 bv = *(const float4*)(bias + d0);
#pragma unroll
  for (int ii = 0; ii < 8; ++ii) { acc[ii][0] = bv.x; acc[ii][1] = bv.y; acc[ii][2] = bv.z; acc[ii][3] = bv.w; }

  for (int kp = 0; kp < 256; kp += 8) {
    __syncthreads();                 // previous panel fully consumed
    {                                // stage 8x256 W panel: 512 threads x 1 float4
      const int r = tid >> 6;
      const int c = (tid & 63) * 4;
      *(float4*)(Wpan + r * 256 + c) = *(const float4*)(W + (kp + r) * 256 + c);
    }
    __syncthreads();
#pragma unroll
    for (int kk = 0; kk < 8; kk += 4) {
      float4 av[8];
#pragma unroll
      for (int ii = 0; ii < 8; ++ii) av[ii] = *(const float4*)(Ain + (i0 + ii) * SA + kp + kk);
      float4 wv[4];
#pragma unroll
      for (int k2 = 0; k2 < 4; ++k2) wv[k2] = *(const float4*)(Wpan + (kk + k2) * 256 + d0);
      fma_8x4(acc, av, wv);
    }
  }
  __syncthreads();
#pragma unroll
  for (int ii = 0; ii < 8; ++ii) {
    float4 o;
    o.x = acc[ii][0]; o.y = acc[ii][1]; o.z = acc[ii][2]; o.w = acc[ii][3];
    if (do_relu) { o.x = fmaxf(o.x, 0.f); o.y = fmaxf(o.y, 0.f); o.z = fmaxf(o.z, 0.f); o.w = fmaxf(o.w, 0.f); }
    *(float4*)(Out + (i0 + ii) * SA + d0) = o;
  }
  __syncthreads();
}

// Out[64][256] = Adj[64][64] @ Hin[64][256] + (1+eps)*Hin   (GIN aggregation, no relu/bias)
__device__ __forceinline__ void gemm_adj(const float* __restrict__ Hin, float* __restrict__ Out,
                                         const float* __restrict__ AdjS, float epsl) {
  const int tid = threadIdx.x;
  const int it = tid >> 6;
  const int dt = tid & 63;
  const int i0 = it * 8;
  const int d0 = dt * 4;
  float acc[8][4];
#pragma unroll
  for (int ii = 0; ii < 8; ++ii) { acc[ii][0] = 0.f; acc[ii][1] = 0.f; acc[ii][2] = 0.f; acc[ii][3] = 0.f; }
#pragma unroll 4
  for (int k = 0; k < 64; k += 4) {
    float4 av[8];
#pragma unroll
    for (int ii = 0; ii < 8; ++ii) av[ii] = *(const float4*)(AdjS + (i0 + ii) * 64 + k);
    float4 wv[4];
#pragma unroll
    for (int k2 = 0; k2 < 4; ++k2) wv[k2] = *(const float4*)(Hin + (k + k2) * SA + d0);
    fma_8x4(acc, av, wv);
  }
#pragma unroll
  for (int ii = 0; ii < 8; ++ii) {
    const float4 hv = *(const float4*)(Hin + (i0 + ii) * SA + d0);
    float4 o;
    o.x = fmaf(epsl, hv.x, acc[ii][0]);
    o.y = fmaf(epsl, hv.y, acc[ii][1]);
    o.z = fmaf(epsl, hv.z, acc[ii][2]);
    o.w = fmaf(epsl, hv.w, acc[ii][3]);
    *(float4*)(Out + (i0 + ii) * SA + d0) = o;
  }
  __syncthreads();
}

// ---------------- small kernels ----------------
__global__ void zero_kernel(float* __restrict__ p, int n) {
  const int i = blockIdx.x * 256 + threadIdx.x;
  if (i < n) p[i] = 0.f;
}

__global__ void build_adj_kernel(const int* __restrict__ esrc, const int* __restrict__ edst,
                                 float* __restrict__ AdjF) {
  const int e = blockIdx.x * 256 + threadIdx.x;
  if (e < E_) {
    const int s = esrc[e];
    const int d = edst[e];
    const int g = s >> 6;
    atomicAdd(AdjF + g * 4096 + (d & 63) * 64 + (s & 63), 1.0f);
  }
}

__global__ __launch_bounds__(256) void enc_kernel(const float* __restrict__ x, const float* __restrict__ Wenc,
                                                  const float* __restrict__ benc, float* __restrict__ h0g) {
  __shared__ float xs[DF_];
  const int n = blockIdx.x;
  const int d = threadIdx.x;
  if (d < DF_) xs[d] = x[n * DF_ + d];
  __syncthreads();
  float acc = benc[d];
#pragma unroll
  for (int k = 0; k < DF_; ++k) acc = fmaf(xs[k], Wenc[k * D_ + d], acc);
  h0g[n * D_ + d] = fmaxf(acc, 0.f);
}

// ---------------- the fused per-graph pipeline ----------------
__global__ __launch_bounds__(512)
void mega_kernel(const float* __restrict__ h0g, const float* __restrict__ AdjF,
                 const float* __restrict__ gW1, const float* __restrict__ gb1,
                 const float* __restrict__ gW2, const float* __restrict__ gb2,
                 const float* __restrict__ eps, const float* __restrict__ aemb,
                 const float* __restrict__ Wn2n, const float* __restrict__ bn2n,
                 const float* __restrict__ Wpred, const float* __restrict__ bpred,
                 float* __restrict__ outp) {
  __shared__ float bufA[64 * SA];     // 66560 B
  __shared__ float bufB[64 * SA];     // 66560 B
  __shared__ float AdjS[64 * 64];     // 16384 B
  __shared__ float Wpan[8 * 256];     //  8192 B
  __shared__ float sqS[64];
  __shared__ float mindS[64];
  __shared__ float scoreS[64];
  __shared__ float hgS[256];
  __shared__ int   anchorS[64];

  const int tid = threadIdx.x;
  const int b = blockIdx.x;
  const int m = blockIdx.y;

  // stage adjacency counts for this graph
  {
    const float* src = AdjF + b * 4096;
    for (int t = tid; t < 1024; t += 512)
      *(float4*)(AdjS + t * 4) = *(const float4*)(src + t * 4);
  }
  if (tid < 64) anchorS[tid] = 0;
  // initial xcur = tx = h0 rows of this graph
  {
    const int i = tid >> 3, part = tid & 7;
    const float* src = h0g + (b * 64 + i) * 256;
    const int dbase = part * 32;
#pragma unroll
    for (int d = 0; d < 32; d += 4)
      *(float4*)(bufA + i * SA + dbase + d) = *(const float4*)(src + dbase + d);
  }
  __syncthreads();

  float* cur = bufA;
  float* oth = bufB;

  for (int iter = 1; iter <= NA_ + 1; ++iter) {
    // ----- 5 GIN layers (h stays in LDS) -----
    for (int l = 0; l < L_; ++l) {
      const float epsl = 1.0f + eps[l];
      gemm_adj(cur, oth, AdjS, epsl);                            // zin = Aeps @ h          (cur -> oth)
      gemm_w(oth, cur, gW1 + l * D_ * D_, gb1 + l * D_, Wpan, true);  // z = relu(zin@W1+b1) (oth -> cur)
      gemm_w(cur, oth, gW2 + l * D_ * D_, gb2 + l * D_, Wpan, true);  // h = relu(z@W2+b2)   (cur -> oth)
      float* t = cur; cur = oth; oth = t;                        // h now in cur
    }
    if (iter == NA_ + 1) break;

    // ----- mindist on cur: sq norms -----
    {
      const int i = tid >> 3, part = tid & 7;
      const int dbase = part * 32;
      float s = 0.f;
#pragma unroll
      for (int d = 0; d < 32; d += 4) {
        const float4 v = *(const float4*)(cur + i * SA + dbase + d);
        s += v.x * v.x + v.y * v.y + v.z * v.z + v.w * v.w;
      }
      s += __shfl_xor(s, 1); s += __shfl_xor(s, 2); s += __shfl_xor(s, 4);
      if (part == 0) sqS[i] = s;
    }
    __syncthreads();
    // ----- pairwise min distance -----
    {
      const int i = tid >> 3, jt = tid & 7;
      float dmin = 3.4e38f;
      for (int jj = 0; jj < 8; ++jj) {
        const int j = jt + jj * 8;
        float dp = 0.f;
#pragma unroll 16
        for (int d = 0; d < 256; d += 4) {
          const float4 a = *(const float4*)(cur + i * SA + d);
          const float4 bb = *(const float4*)(cur + j * SA + d);
          dp += a.x * bb.x + a.y * bb.y + a.z * bb.z + a.w * bb.w;
        }
        float d2 = sqS[i] + sqS[j] - 2.f * dp;
        d2 = fmaxf(d2, 0.f);
        if (j == i) d2 += 1e9f;
        dmin = fminf(dmin, d2);
      }
      dmin = fminf(dmin, __shfl_xor(dmin, 1));
      dmin = fminf(dmin, __shfl_xor(dmin, 2));
      dmin = fminf(dmin, __shfl_xor(dmin, 4));
      if (jt == 0) mindS[i] = dmin;
    }
    __syncthreads();
    // ----- Gumbel-argmax sampling (exact JAX threefry) -----
    if (tid < 64) {
      const int j = tid;
      uint32_t k0, k1;
      threefry2x32(0u, 42u, 0u, (uint32_t)iter, k0, k1);   // fold_in(key(42), iter)
      const uint32_t p = (uint32_t)(m * (B_ * NPG_) + b * NPG_ + j);
      uint32_t o0, o1, bits;
      if (p < 32768u) { threefry2x32(k0, k1, p, p + 32768u, o0, o1); bits = o0; }
      else            { threefry2x32(k0, k1, p - 32768u, p, o0, o1); bits = o1; }
      const float f = __uint_as_float((bits >> 9) | 0x3f800000u) - 1.0f;
      const float uv = fmaxf(1e-9f, f + 1e-9f);
      const float pred = -mindS[j] - ((anchorS[j] > 0) ? 10.0f : 0.0f);
      scoreS[j] = pred - logf(-logf(uv));
    }
    __syncthreads();
    if (tid == 0) {                        // first-max argmax (matches jnp.argmax)
      int best = 0; float bv = scoreS[0];
      for (int j = 1; j < 64; ++j) { const float v = scoreS[j]; if (v > bv) { bv = v; best = j; } }
      anchorS[best] = iter;
    }
    __syncthreads();
    // ----- xcur = tx * anchor_emb[anchor] + tx  (into cur) -----
    {
      const int i = tid >> 3, part = tid & 7;
      const float* t = h0g + (b * 64 + i) * 256;
      const float* e = aemb + anchorS[i] * D_;
      const int dbase = part * 32;
#pragma unroll
      for (int d = 0; d < 32; d += 4) {
        const float4 tv = *(const float4*)(t + dbase + d);
        const float4 ev = *(const float4*)(e + dbase + d);
        float4 r;
        r.x = fmaf(tv.x, ev.x, tv.x);
        r.y = fmaf(tv.y, ev.y, tv.y);
        r.z = fmaf(tv.z, ev.z, tv.z);
        r.w = fmaf(tv.w, ev.w, tv.w);
        *(float4*)(cur + i * SA + dbase + d) = r;
      }
    }
    __syncthreads();
  }

  // ----- head: hn = relu(h @ W_n2n + b_n2n) -----
  gemm_w(cur, oth, Wn2n, bn2n, Wpan, true);   // hn in oth
  // hg = mean over 64 nodes
  if (tid < 256) {
    float s = 0.f;
    for (int i = 0; i < 64; ++i) s += oth[i * SA + tid];
    hgS[tid] = s * (1.0f / 64.0f);
  }
  __syncthreads();
  // out[b][t] += 0.25 * (hg . Wpred[:,t])  (+ b_pred once, via m==0)
  if (tid < 160) {
    const int t = tid >> 4, part = tid & 15;
    float s = 0.f;
    for (int d = part * 16; d < part * 16 + 16; ++d) s = fmaf(hgS[d], Wpred[d * TASKS_ + t], s);
    s += __shfl_xor(s, 1); s += __shfl_xor(s, 2); s += __shfl_xor(s, 4); s += __shfl_xor(s, 8);
    if (part == 0) {
      float val = s * 0.25f;
      if (m == 0) val += bpred[t];
      atomicAdd(outp + b * TASKS_ + t, val);
    }
  }
}

// ---------------- launch ----------------
extern "C" void kernel_launch(void* const* d_in, const int* in_sizes, int n_in,
                              void* d_out, int out_size, void* d_ws, size_t ws_size,
                              hipStream_t stream) {
  const float* x     = (const float*)d_in[0];
  const float* Wenc  = (const float*)d_in[1];
  const float* benc  = (const float*)d_in[2];
  const float* gW1   = (const float*)d_in[3];
  const float* gb1   = (const float*)d_in[4];
  const float* gW2   = (const float*)d_in[5];
  const float* gb2   = (const float*)d_in[6];
  const float* eps   = (const float*)d_in[7];
  const float* aemb  = (const float*)d_in[8];
  const float* Wn2n  = (const float*)d_in[9];
  const float* bn2n  = (const float*)d_in[10];
  const float* Wpred = (const float*)d_in[11];
  const float* bpred = (const float*)d_in[12];
  const int* esrc    = (const int*)d_in[13];
  const int* edst    = (const int*)d_in[14];
  float* outp = (float*)d_out;

  float* h0g  = (float*)d_ws;                 // N*D floats   (16 MB)
  float* AdjF = h0g + (size_t)N_ * D_;        // B*64*64      (4 MB)

  zero_kernel<<<dim3((B_ * 4096 + 255) / 256), dim3(256), 0, stream>>>(AdjF, B_ * 4096);
  zero_kernel<<<dim3((out_size + 255) / 256), dim3(256), 0, stream>>>(outp, out_size);
  build_adj_kernel<<<dim3((E_ + 255) / 256), dim3(256), 0, stream>>>(esrc, edst, AdjF);
  enc_kernel<<<dim3(N_), dim3(256), 0, stream>>>(x, Wenc, benc, h0g);
  mega_kernel<<<dim3(B_, M_), dim3(512), 0, stream>>>(h0g, AdjF, gW1, gb1, gW2, gb2,
                                                      eps, aemb, Wn2n, bn2n, Wpred, bpred, outp);
}

// Round 2
// 2460.527 us; speedup vs baseline: 1.8149x; 1.8149x over previous
//
#include <hip/hip_runtime.h>
#include <stdint.h>

typedef unsigned short ushort_t;

// Problem constants (match reference)
#define M_     4
#define B_     256
#define NPG_   64
#define N_     (B_*NPG_)    // 16384
#define DEG_   8
#define E_     (N_*DEG_)    // 131072
#define DF_    16
#define D_     256
#define L_     5
#define NA_    2
#define TASKS_ 10

#define SA 260   // padded LDS row stride (floats) for the 64x256 node buffer

typedef short bf16x8 __attribute__((ext_vector_type(8)));    // 8 bf16 = 4 VGPRs
typedef float f32x16 __attribute__((ext_vector_type(16)));   // MFMA 32x32 acc

// ---------------- bf16 split helpers ----------------
__device__ __forceinline__ ushort_t f2bf_rne(float x) {
  uint32_t u = __float_as_uint(x);
  uint32_t r = (u + 0x7fffu + ((u >> 16) & 1u)) >> 16;   // round-nearest-even
  return (ushort_t)r;
}
__device__ __forceinline__ float bf2f(ushort_t h) { return __uint_as_float(((uint32_t)h) << 16); }

__device__ __forceinline__ void split8(const float4 a, const float4 b, bf16x8& hi, bf16x8& lo) {
  float v[8] = {a.x, a.y, a.z, a.w, b.x, b.y, b.z, b.w};
#pragma unroll
  for (int j = 0; j < 8; ++j) {
    const ushort_t h = f2bf_rne(v[j]);
    const ushort_t l = f2bf_rne(v[j] - bf2f(h));
    hi[j] = (short)h;
    lo[j] = (short)l;
  }
}

// ---------------- async global->LDS (16B per lane) ----------------
typedef __attribute__((address_space(1))) const unsigned char glob_u8;
typedef __attribute__((address_space(3))) unsigned char lds_u8;
__device__ __forceinline__ void async_cp16(const void* g, void* l) {
  __builtin_amdgcn_global_load_lds((glob_u8*)g, (lds_u8*)l, 16, 0, 0);
}

// ---------------- Threefry-2x32 (exact JAX semantics) ----------------
__device__ __forceinline__ uint32_t rotl32(uint32_t v, int r) { return (v << r) | (v >> (32 - r)); }

__device__ __forceinline__ void threefry2x32(uint32_t k0, uint32_t k1, uint32_t x0, uint32_t x1,
                                             uint32_t& o0, uint32_t& o1) {
  const uint32_t ks2 = k0 ^ k1 ^ 0x1BD11BDAu;
  x0 += k0; x1 += k1;
#define TFR(r) { x0 += x1; x1 = rotl32(x1, r); x1 ^= x0; }
  TFR(13) TFR(15) TFR(26) TFR(6)   x0 += k1;  x1 += ks2 + 1u;
  TFR(17) TFR(29) TFR(16) TFR(24)  x0 += ks2; x1 += k0 + 2u;
  TFR(13) TFR(15) TFR(26) TFR(6)   x0 += k0;  x1 += k1 + 3u;
  TFR(17) TFR(29) TFR(16) TFR(24)  x0 += k1;  x1 += ks2 + 4u;
  TFR(13) TFR(15) TFR(26) TFR(6)   x0 += ks2; x1 += k0 + 5u;
#undef TFR
  o0 = x0; o1 = x1;
}

// ---------------- 8x4 register-tile FMA (fp32, for gemm_adj) ----------------
__device__ __forceinline__ void fma_8x4(float (&acc)[8][4], const float4 (&av)[8], const float4 (&wv)[4]) {
#pragma unroll
  for (int ii = 0; ii < 8; ++ii) {
    const float4 a_ = av[ii];
    acc[ii][0] = fmaf(a_.x, wv[0].x, acc[ii][0]);
    acc[ii][1] = fmaf(a_.x, wv[0].y, acc[ii][1]);
    acc[ii][2] = fmaf(a_.x, wv[0].z, acc[ii][2]);
    acc[ii][3] = fmaf(a_.x, wv[0].w, acc[ii][3]);
    acc[ii][0] = fmaf(a_.y, wv[1].x, acc[ii][0]);
    acc[ii][1] = fmaf(a_.y, wv[1].y, acc[ii][1]);
    acc[ii][2] = fmaf(a_.y, wv[1].z, acc[ii][2]);
    acc[ii][3] = fmaf(a_.y, wv[1].w, acc[ii][3]);
    acc[ii][0] = fmaf(a_.z, wv[2].x, acc[ii][0]);
    acc[ii][1] = fmaf(a_.z, wv[2].y, acc[ii][1]);
    acc[ii][2] = fmaf(a_.z, wv[2].z, acc[ii][2]);
    acc[ii][3] = fmaf(a_.z, wv[2].w, acc[ii][3]);
    acc[ii][0] = fmaf(a_.w, wv[3].x, acc[ii][0]);
    acc[ii][1] = fmaf(a_.w, wv[3].y, acc[ii][1]);
    acc[ii][2] = fmaf(a_.w, wv[3].z, acc[ii][2]);
    acc[ii][3] = fmaf(a_.w, wv[3].w, acc[ii][3]);
  }
}

// ---------------- MFMA gemm: h[64][256] = relu(h @ W + b), in-place ----------------
// WTmat: [2(hi/lo)][256 col][256 k] bf16 (transposed, pre-split).
// Pan (LDS): double-buffered panels, each panel = [hi/lo][4 chunk][256 col] x 16B frags.
#define PAN_FRAGS 2048                 // frags per panel (hi+lo): 2*4*256
__device__ __forceinline__ void stage_panel(ushort_t* panLds, const ushort_t* WTmat, int p, int tid) {
#pragma unroll
  for (int s = 0; s < 4; ++s) {
    const int f = s * 512 + tid;                 // 0..2047
    const int hl = f >> 10;
    const int chunk = (f >> 8) & 3;
    const int col = f & 255;
    const ushort_t* g = WTmat + hl * 65536 + col * 256 + p * 32 + chunk * 8;
    async_cp16((const void*)g, (void*)(panLds + f * 8));
  }
}

__device__ __forceinline__ void gemm_w_mfma(float* __restrict__ h, const ushort_t* __restrict__ WTmat,
                                            const float* __restrict__ bias, ushort_t* __restrict__ Pan,
                                            bool do_relu) {
  const int tid  = threadIdx.x;
  const int lane = tid & 63;
  const int w    = tid >> 6;
  const int rb   = w & 1;              // row-block (32 rows)
  const int cb0  = (w >> 1) * 2;       // first of 2 col-blocks (32 cols each)
  const int l31  = lane & 31;
  const int lh   = lane >> 5;          // 0/1

  f32x16 acc0 = {};
  f32x16 acc1 = {};

  stage_panel(Pan, WTmat, 0, tid);
  __syncthreads();

  for (int p = 0; p < 8; ++p) {        // K panels of 32
    if (p < 7) stage_panel(Pan + ((p + 1) & 1) * PAN_FRAGS * 8, WTmat, p + 1, tid);
    const ushort_t* pan = Pan + (p & 1) * PAN_FRAGS * 8;
    const float* arow = h + (rb * 32 + l31) * SA + p * 32 + lh * 8;
#pragma unroll
    for (int q = 0; q < 2; ++q) {      // two k16 halves
      const float4 a0 = *(const float4*)(arow + q * 16);
      const float4 a1 = *(const float4*)(arow + q * 16 + 4);
      bf16x8 ahi, alo;
      split8(a0, a1, ahi, alo);
      const int chunk = q * 2 + lh;
#pragma unroll
      for (int t = 0; t < 2; ++t) {
        const int col = (cb0 + t) * 32 + l31;
        const bf16x8 bhi = *(const bf16x8*)(pan + (size_t)(chunk * 256 + col) * 8);
        const bf16x8 blo = *(const bf16x8*)(pan + (size_t)((4 + chunk) * 256 + col) * 8);
        if (t == 0) {
          acc0 = __builtin_amdgcn_mfma_f32_32x32x16_bf16(ahi, bhi, acc0, 0, 0, 0);
          acc0 = __builtin_amdgcn_mfma_f32_32x32x16_bf16(ahi, blo, acc0, 0, 0, 0);
          acc0 = __builtin_amdgcn_mfma_f32_32x32x16_bf16(alo, bhi, acc0, 0, 0, 0);
        } else {
          acc1 = __builtin_amdgcn_mfma_f32_32x32x16_bf16(ahi, bhi, acc1, 0, 0, 0);
          acc1 = __builtin_amdgcn_mfma_f32_32x32x16_bf16(ahi, blo, acc1, 0, 0, 0);
          acc1 = __builtin_amdgcn_mfma_f32_32x32x16_bf16(alo, bhi, acc1, 0, 0, 0);
        }
      }
    }
    __syncthreads();                   // panel p consumed; panel p+1 landed (vmcnt drain)
  }

  // all A reads complete (barrier above) -> in-place write back
#pragma unroll
  for (int t = 0; t < 2; ++t) {
    const int col = (cb0 + t) * 32 + l31;
    const float bv = bias[col];
    const f32x16 acc = t ? acc1 : acc0;
#pragma unroll
    for (int r = 0; r < 16; ++r) {
      const int row = rb * 32 + (r & 3) + 8 * (r >> 2) + 4 * lh;
      float v = acc[r] + bv;
      if (do_relu) v = fmaxf(v, 0.f);
      h[row * SA + col] = v;
    }
  }
  __syncthreads();
}

// ---------------- fp32 GIN aggregation, in-place: h = Adj@h + (1+eps)*h ----------------
__device__ __forceinline__ void gemm_adj_ip(float* __restrict__ h, const float* __restrict__ AdjS, float epsl) {
  const int tid = threadIdx.x;
  const int i0 = (tid >> 6) * 8;
  const int d0 = (tid & 63) * 4;
  float acc[8][4];
#pragma unroll
  for (int ii = 0; ii < 8; ++ii) { acc[ii][0] = 0.f; acc[ii][1] = 0.f; acc[ii][2] = 0.f; acc[ii][3] = 0.f; }
#pragma unroll 4
  for (int k = 0; k < 64; k += 4) {
    float4 av[8];
#pragma unroll
    for (int ii = 0; ii < 8; ++ii) av[ii] = *(const float4*)(AdjS + (i0 + ii) * 64 + k);
    float4 wv[4];
#pragma unroll
    for (int k2 = 0; k2 < 4; ++k2) wv[k2] = *(const float4*)(h + (k + k2) * SA + d0);
    fma_8x4(acc, av, wv);
  }
  float4 hv[8];
#pragma unroll
  for (int ii = 0; ii < 8; ++ii) hv[ii] = *(const float4*)(h + (i0 + ii) * SA + d0);
  __syncthreads();                     // all reads done before in-place write
#pragma unroll
  for (int ii = 0; ii < 8; ++ii) {
    float4 o;
    o.x = fmaf(epsl, hv[ii].x, acc[ii][0]);
    o.y = fmaf(epsl, hv[ii].y, acc[ii][1]);
    o.z = fmaf(epsl, hv[ii].z, acc[ii][2]);
    o.w = fmaf(epsl, hv[ii].w, acc[ii][3]);
    *(float4*)(h + (i0 + ii) * SA + d0) = o;
  }
  __syncthreads();
}

// ---------------- small kernels ----------------
__global__ void zero_kernel(float* __restrict__ p, int n) {
  const int i = blockIdx.x * 256 + threadIdx.x;
  if (i < n) p[i] = 0.f;
}

__global__ void build_adj_kernel(const int* __restrict__ esrc, const int* __restrict__ edst,
                                 float* __restrict__ AdjF) {
  const int e = blockIdx.x * 256 + threadIdx.x;
  if (e < E_) {
    const int s = esrc[e];
    const int d = edst[e];
    const int g = s >> 6;
    atomicAdd(AdjF + g * 4096 + (d & 63) * 64 + (s & 63), 1.0f);
  }
}

__global__ __launch_bounds__(256) void enc_kernel(const float* __restrict__ x, const float* __restrict__ Wenc,
                                                  const float* __restrict__ benc, float* __restrict__ h0g) {
  __shared__ float xs[DF_];
  const int n = blockIdx.x;
  const int d = threadIdx.x;
  if (d < DF_) xs[d] = x[n * DF_ + d];
  __syncthreads();
  float acc = benc[d];
#pragma unroll
  for (int k = 0; k < DF_; ++k) acc = fmaf(xs[k], Wenc[k * D_ + d], acc);
  h0g[n * D_ + d] = fmaxf(acc, 0.f);
}

// Pre-split + transpose weights: WTbuf[mat][hi/lo][col d][k] bf16 from W[mat][k][d] fp32.
// mat: 0..4 = gin_W1[l], 5..9 = gin_W2[l], 10 = W_n2n
__global__ __launch_bounds__(256) void prep_wt(const float* __restrict__ gW1, const float* __restrict__ gW2,
                                               const float* __restrict__ Wn2n, ushort_t* __restrict__ WTbuf) {
  const int mat = blockIdx.y;
  const int ds = blockIdx.x;                 // 32-wide d slab
  const float* Wsrc = (mat < 5) ? (gW1 + mat * 65536)
                    : (mat < 10) ? (gW2 + (mat - 5) * 65536) : Wn2n;
  __shared__ float t[32 * 260];
  const int tid = threadIdx.x;
  for (int k0 = 0; k0 < 256; k0 += 8) {
    const int k = k0 + (tid >> 5);
    const int dl = tid & 31;
    t[dl * 260 + k] = Wsrc[k * 256 + ds * 32 + dl];
  }
  __syncthreads();
  ushort_t* dst = WTbuf + (size_t)mat * 131072;
  const int dp = tid >> 3;
  const int kb = (tid & 7) * 32;
  const int d = ds * 32 + dp;
  for (int k = kb; k < kb + 32; ++k) {
    const float a = t[dp * 260 + k];
    const ushort_t hi = f2bf_rne(a);
    const ushort_t lo = f2bf_rne(a - bf2f(hi));
    dst[d * 256 + k] = hi;
    dst[65536 + d * 256 + k] = lo;
  }
}

// ---------------- fused per-graph pipeline ----------------
__global__ __launch_bounds__(512)
void mega_kernel(const float* __restrict__ h0g, const float* __restrict__ AdjF,
                 const ushort_t* __restrict__ WTbuf,
                 const float* __restrict__ gb1, const float* __restrict__ gb2,
                 const float* __restrict__ eps, const float* __restrict__ aemb,
                 const float* __restrict__ bn2n,
                 const float* __restrict__ Wpred, const float* __restrict__ bpred,
                 float* __restrict__ outp) {
  __shared__ float4 hV[64 * SA / 4];             // 66560 B, node features (in-place)
  __shared__ ulong2 PanQ[2 * PAN_FRAGS];         // 65536 B, double-buffered W panels
  __shared__ float AdjS[64 * 64];                // 16384 B
  __shared__ float sqS[64];
  __shared__ float mindS[64];
  __shared__ float scoreS[64];
  __shared__ float hgS[256];
  __shared__ int   anchorS[64];

  float* h = (float*)hV;
  ushort_t* Pan = (ushort_t*)PanQ;

  const int tid = threadIdx.x;
  const int b = blockIdx.x;
  const int m = blockIdx.y;

  {
    const float* src = AdjF + b * 4096;
    for (int t = tid; t < 1024; t += 512)
      *(float4*)(AdjS + t * 4) = *(const float4*)(src + t * 4);
  }
  if (tid < 64) anchorS[tid] = 0;
  {
    const int i = tid >> 3, part = tid & 7;
    const float* src = h0g + (b * 64 + i) * 256;
    const int dbase = part * 32;
#pragma unroll
    for (int d = 0; d < 32; d += 4)
      *(float4*)(h + i * SA + dbase + d) = *(const float4*)(src + dbase + d);
  }
  __syncthreads();

  for (int iter = 1; iter <= NA_ + 1; ++iter) {
    // ----- 5 GIN layers, all in-place on h -----
    for (int l = 0; l < L_; ++l) {
      const float epsl = 1.0f + eps[l];
      gemm_adj_ip(h, AdjS, epsl);
      gemm_w_mfma(h, WTbuf + (size_t)l * 131072,       gb1 + l * D_, Pan, true);
      gemm_w_mfma(h, WTbuf + (size_t)(5 + l) * 131072, gb2 + l * D_, Pan, true);
    }
    if (iter == NA_ + 1) break;

    // ----- mindist: sq norms -----
    {
      const int i = tid >> 3, part = tid & 7;
      const int dbase = part * 32;
      float s = 0.f;
#pragma unroll
      for (int d = 0; d < 32; d += 4) {
        const float4 v = *(const float4*)(h + i * SA + dbase + d);
        s += v.x * v.x + v.y * v.y + v.z * v.z + v.w * v.w;
      }
      s += __shfl_xor(s, 1); s += __shfl_xor(s, 2); s += __shfl_xor(s, 4);
      if (part == 0) sqS[i] = s;
    }
    __syncthreads();
    // ----- pairwise min distance -----
    {
      const int i = tid >> 3, jt = tid & 7;
      float dmin = 3.4e38f;
      for (int jj = 0; jj < 8; ++jj) {
        const int j = jt + jj * 8;
        float dp = 0.f;
#pragma unroll 16
        for (int d = 0; d < 256; d += 4) {
          const float4 a = *(const float4*)(h + i * SA + d);
          const float4 bb = *(const float4*)(h + j * SA + d);
          dp += a.x * bb.x + a.y * bb.y + a.z * bb.z + a.w * bb.w;
        }
        float d2 = sqS[i] + sqS[j] - 2.f * dp;
        d2 = fmaxf(d2, 0.f);
        if (j == i) d2 += 1e9f;
        dmin = fminf(dmin, d2);
      }
      dmin = fminf(dmin, __shfl_xor(dmin, 1));
      dmin = fminf(dmin, __shfl_xor(dmin, 2));
      dmin = fminf(dmin, __shfl_xor(dmin, 4));
      if (jt == 0) mindS[i] = dmin;
    }
    __syncthreads();
    // ----- Gumbel-argmax sampling (exact JAX threefry) -----
    if (tid < 64) {
      const int j = tid;
      uint32_t k0, k1;
      threefry2x32(0u, 42u, 0u, (uint32_t)iter, k0, k1);
      const uint32_t p = (uint32_t)(m * (B_ * NPG_) + b * NPG_ + j);
      uint32_t o0, o1, bits;
      if (p < 32768u) { threefry2x32(k0, k1, p, p + 32768u, o0, o1); bits = o0; }
      else            { threefry2x32(k0, k1, p - 32768u, p, o0, o1); bits = o1; }
      const float f = __uint_as_float((bits >> 9) | 0x3f800000u) - 1.0f;
      const float uv = fmaxf(1e-9f, f + 1e-9f);
      const float pred = -mindS[j] - ((anchorS[j] > 0) ? 10.0f : 0.0f);
      scoreS[j] = pred - logf(-logf(uv));
    }
    __syncthreads();
    if (tid == 0) {
      int best = 0; float bv = scoreS[0];
      for (int j = 1; j < 64; ++j) { const float v = scoreS[j]; if (v > bv) { bv = v; best = j; } }
      anchorS[best] = iter;
    }
    __syncthreads();
    // ----- xcur = tx * anchor_emb[anchor] + tx -----
    {
      const int i = tid >> 3, part = tid & 7;
      const float* t = h0g + (b * 64 + i) * 256;
      const float* e = aemb + anchorS[i] * D_;
      const int dbase = part * 32;
#pragma unroll
      for (int d = 0; d < 32; d += 4) {
        const float4 tv = *(const float4*)(t + dbase + d);
        const float4 ev = *(const float4*)(e + dbase + d);
        float4 r;
        r.x = fmaf(tv.x, ev.x, tv.x);
        r.y = fmaf(tv.y, ev.y, tv.y);
        r.z = fmaf(tv.z, ev.z, tv.z);
        r.w = fmaf(tv.w, ev.w, tv.w);
        *(float4*)(h + i * SA + dbase + d) = r;
      }
    }
    __syncthreads();
  }

  // ----- head: hn = relu(h @ W_n2n + b_n2n), in-place -----
  gemm_w_mfma(h, WTbuf + (size_t)10 * 131072, bn2n, Pan, true);
  if (tid < 256) {
    float s = 0.f;
    for (int i = 0; i < 64; ++i) s += h[i * SA + tid];
    hgS[tid] = s * (1.0f / 64.0f);
  }
  __syncthreads();
  if (tid < 160) {
    const int t = tid >> 4, part = tid & 15;
    float s = 0.f;
    for (int d = part * 16; d < part * 16 + 16; ++d) s = fmaf(hgS[d], Wpred[d * TASKS_ + t], s);
    s += __shfl_xor(s, 1); s += __shfl_xor(s, 2); s += __shfl_xor(s, 4); s += __shfl_xor(s, 8);
    if (part == 0) {
      float val = s * 0.25f;
      if (m == 0) val += bpred[t];
      atomicAdd(outp + b * TASKS_ + t, val);
    }
  }
}

// ---------------- launch ----------------
extern "C" void kernel_launch(void* const* d_in, const int* in_sizes, int n_in,
                              void* d_out, int out_size, void* d_ws, size_t ws_size,
                              hipStream_t stream) {
  const float* x     = (const float*)d_in[0];
  const float* Wenc  = (const float*)d_in[1];
  const float* benc  = (const float*)d_in[2];
  const float* gW1   = (const float*)d_in[3];
  const float* gb1   = (const float*)d_in[4];
  const float* gW2   = (const float*)d_in[5];
  const float* gb2   = (const float*)d_in[6];
  const float* eps   = (const float*)d_in[7];
  const float* aemb  = (const float*)d_in[8];
  const float* Wn2n  = (const float*)d_in[9];
  const float* bn2n  = (const float*)d_in[10];
  const float* Wpred = (const float*)d_in[11];
  const float* bpred = (const float*)d_in[12];
  const int* esrc    = (const int*)d_in[13];
  const int* edst    = (const int*)d_in[14];
  float* outp = (float*)d_out;

  float* h0g  = (float*)d_ws;                         // 16 MB
  float* AdjF = h0g + (size_t)N_ * D_;                // 4 MB
  ushort_t* WTbuf = (ushort_t*)(AdjF + B_ * 4096);    // 11 * 256 KB bf16 split weights

  zero_kernel<<<dim3((B_ * 4096 + 255) / 256), dim3(256), 0, stream>>>(AdjF, B_ * 4096);
  zero_kernel<<<dim3((out_size + 255) / 256), dim3(256), 0, stream>>>(outp, out_size);
  build_adj_kernel<<<dim3((E_ + 255) / 256), dim3(256), 0, stream>>>(esrc, edst, AdjF);
  enc_kernel<<<dim3(N_), dim3(256), 0, stream>>>(x, Wenc, benc, h0g);
  prep_wt<<<dim3(8, 11), dim3(256), 0, stream>>>(gW1, gW2, Wn2n, WTbuf);
  mega_kernel<<<dim3(B_, M_), dim3(512), 0, stream>>>(h0g, AdjF, WTbuf, gb1, gb2,
                                                      eps, aemb, bn2n, Wpred, bpred, outp);
}

// Round 5
// 1145.663 us; speedup vs baseline: 3.8978x; 2.1477x over previous
//
#include <hip/hip_runtime.h>
#include <stdint.h>

typedef unsigned short u16;
typedef _Float16 f16;
typedef f16 f16x8 __attribute__((ext_vector_type(8)));
typedef float f32x16 __attribute__((ext_vector_type(16)));

// Problem constants
#define M_     4
#define B_     256
#define NPG_   64
#define N_     (B_*NPG_)    // 16384
#define DEG_   8
#define E_     (N_*DEG_)    // 131072
#define DF_    16
#define D_     256
#define L_     5
#define NA_    2
#define TASKS_ 10

#define HROW 520            // u16 row stride of split-h buffer (1040 B, 16B aligned)
#define MFMA16(a,b,c) __builtin_amdgcn_mfma_f32_32x32x16_f16(a,b,c,0,0,0)

// ---------------- f16 helpers ----------------
__device__ __forceinline__ u16 h_bits(f16 h) { union { f16 h; u16 u; } c; c.h = h; return c.u; }
__device__ __forceinline__ f16 bits_h(u16 u) { union { u16 u; f16 h; } c; c.u = u; return c.h; }
__device__ __forceinline__ float h2f(u16 u) { return (float)bits_h(u); }
__device__ __forceinline__ void split_f16(float v, u16& hi, u16& lo) {
  f16 h = (f16)v;
  f16 l = (f16)(v - (float)h);
  hi = h_bits(h); lo = h_bits(l);
}

// u16 index of the 8-elem hi group for (row, chunk); lo group at +8. XOR swizzle on chunk.
__device__ __forceinline__ int haddr8(int row, int chunk) {
  return row * HROW + ((chunk ^ (row & 7)) << 4);
}
__device__ __forceinline__ void write_split(u16* hfU, int row, int col, float v) {
  const int ad = haddr8(row, col >> 3) + (col & 7);
  u16 hi, lo; split_f16(v, hi, lo);
  hfU[ad] = hi; hfU[ad + 8] = lo;
}

// ---------------- Threefry-2x32 (exact JAX semantics) ----------------
__device__ __forceinline__ uint32_t rotl32(uint32_t v, int r) { return (v << r) | (v >> (32 - r)); }
__device__ __forceinline__ void threefry2x32(uint32_t k0, uint32_t k1, uint32_t x0, uint32_t x1,
                                             uint32_t& o0, uint32_t& o1) {
  const uint32_t ks2 = k0 ^ k1 ^ 0x1BD11BDAu;
  x0 += k0; x1 += k1;
#define TFR(r) { x0 += x1; x1 = rotl32(x1, r); x1 ^= x0; }
  TFR(13) TFR(15) TFR(26) TFR(6)   x0 += k1;  x1 += ks2 + 1u;
  TFR(17) TFR(29) TFR(16) TFR(24)  x0 += ks2; x1 += k0 + 2u;
  TFR(13) TFR(15) TFR(26) TFR(6)   x0 += k0;  x1 += k1 + 3u;
  TFR(17) TFR(29) TFR(16) TFR(24)  x0 += k1;  x1 += ks2 + 4u;
  TFR(13) TFR(15) TFR(26) TFR(6)   x0 += ks2; x1 += k0 + 5u;
#undef TFR
  o0 = x0; o1 = x1;
}

// ---------------- MFMA gemm: h = relu?(h @ W + b), in-place on split-h ----------------
// Wave w owns col-block w (cols 32w..32w+31) for BOTH row-blocks; full K (no k-split).
// WTm layout (u16): off = hilo*65536 + (k>>3)*2048 + col*8 + (k&7). B loads coalesced
// (32 lanes x 16B contiguous). Each W frag loaded exactly once per block.
__device__ __forceinline__ void gemm_w_mfma(u16* __restrict__ hfU, const u16* __restrict__ WTm,
                                            const float* __restrict__ bias, bool do_relu) {
  const int tid = threadIdx.x;
  const int lane = tid & 63, w = tid >> 6;
  const int l31 = lane & 31, lh = lane >> 5;
  const int col = w * 32 + l31;
  const float bv = bias[col];

  f32x16 acc0 = {}, acc1 = {};
  const u16* Bbase = WTm + col * 8;
#pragma unroll
  for (int ks = 0; ks < 16; ++ks) {
    const int chunk = ks * 2 + lh;                 // k = 8*chunk + e
    const int a0 = haddr8(l31, chunk);
    const int a1 = haddr8(32 + l31, chunk);
    const f16x8 ahi0 = *(const f16x8*)(hfU + a0);
    const f16x8 alo0 = *(const f16x8*)(hfU + a0 + 8);
    const f16x8 ahi1 = *(const f16x8*)(hfU + a1);
    const f16x8 alo1 = *(const f16x8*)(hfU + a1 + 8);
    const f16x8 bh = *(const f16x8*)(Bbase + chunk * 2048);
    const f16x8 bl = *(const f16x8*)(Bbase + chunk * 2048 + 65536);
    acc0 = MFMA16(ahi0, bh, acc0);
    acc0 = MFMA16(ahi0, bl, acc0);
    acc0 = MFMA16(alo0, bh, acc0);
    acc1 = MFMA16(ahi1, bh, acc1);
    acc1 = MFMA16(ahi1, bl, acc1);
    acc1 = MFMA16(alo1, bh, acc1);
  }
  __syncthreads();                       // S1: all A reads done, h region dead
#pragma unroll
  for (int r = 0; r < 16; ++r) {
    const int rr = (r & 3) + 8 * (r >> 2) + 4 * lh;
    float v0 = acc0[r] + bv;
    float v1 = acc1[r] + bv;
    if (do_relu) { v0 = fmaxf(v0, 0.f); v1 = fmaxf(v1, 0.f); }
    write_split(hfU, rr, col, v0);       // rows 0..31
    write_split(hfU, 32 + rr, col, v1);  // rows 32..63
  }
  __syncthreads();                       // S2: new h ready
}

// ---------------- GIN aggregation via MFMA: h = Adj@h + (1+eps)h, in-place ----------------
__device__ __forceinline__ void gemm_adj_mfma(u16* __restrict__ hfU, const u16* __restrict__ AdjU,
                                              float epsl) {
  const int tid = threadIdx.x;
  const int lane = tid & 63, w = tid >> 6;
  const int l31 = lane & 31, lh = lane >> 5;
  const int d = w * 32 + l31;
  const int dc = d >> 3, de = d & 7;
  f32x16 acc0 = {}, acc1 = {};
#pragma unroll
  for (int kk = 0; kk < 4; ++kk) {
    const f16x8 A0 = *(const f16x8*)(AdjU + l31 * 72 + (kk * 2 + lh) * 8);
    const f16x8 A1 = *(const f16x8*)(AdjU + (32 + l31) * 72 + (kk * 2 + lh) * 8);
    const int jb = kk * 16 + lh * 8;
    f16x8 bh, bl;
#pragma unroll
    for (int jj = 0; jj < 8; ++jj) {
      const int j = jb + jj;
      const int ad = j * HROW + (((dc) ^ (j & 7)) << 4) + de;
      bh[jj] = bits_h(hfU[ad]);
      bl[jj] = bits_h(hfU[ad + 8]);
    }
    acc0 = MFMA16(A0, bh, acc0);
    acc0 = MFMA16(A0, bl, acc0);
    acc1 = MFMA16(A1, bh, acc1);
    acc1 = MFMA16(A1, bl, acc1);
  }
  // self term (1+eps)*h, read before h is overwritten (u16 loads, same type as writes)
  float self0[16], self1[16];
#pragma unroll
  for (int r = 0; r < 16; ++r) {
    const int rr = (r & 3) + 8 * (r >> 2) + 4 * lh;
    { const int ad = rr * HROW + ((dc ^ (rr & 7)) << 4) + de;
      self0[r] = h2f(hfU[ad]) + h2f(hfU[ad + 8]); }
    { const int r1 = 32 + rr; const int ad = r1 * HROW + ((dc ^ (r1 & 7)) << 4) + de;
      self1[r] = h2f(hfU[ad]) + h2f(hfU[ad + 8]); }
  }
  __syncthreads();                       // S1: all reads done
#pragma unroll
  for (int r = 0; r < 16; ++r) {
    const int rr = (r & 3) + 8 * (r >> 2) + 4 * lh;
    write_split(hfU, rr, d, acc0[r] + epsl * self0[r]);
    write_split(hfU, 32 + rr, d, acc1[r] + epsl * self1[r]);
  }
  __syncthreads();                       // S2
}

// ---------------- mindist via Gram matrix G = h h^T (MFMA), h dead afterwards ----------------
__device__ __forceinline__ void mindist_mfma(u16* __restrict__ hfU, float* __restrict__ mindS) {
  const int tid = threadIdx.x;
  const int lane = tid & 63, w = tid >> 6;
  const int gb = w & 3, gi = gb >> 1, gj = gb & 1, ks = w >> 2;
  const int l31 = lane & 31, lh = lane >> 5;
  f32x16 acc = {};
#pragma unroll
  for (int t = 0; t < 8; ++t) {
    const int chunk = 4 * t + 2 * ks + lh;
    const int ra = haddr8(gi * 32 + l31, chunk);
    const int rb_ = haddr8(gj * 32 + l31, chunk);
    const f16x8 ahi = *(const f16x8*)(hfU + ra);
    const f16x8 alo = *(const f16x8*)(hfU + ra + 8);
    const f16x8 bhi = *(const f16x8*)(hfU + rb_);
    const f16x8 blo = *(const f16x8*)(hfU + rb_ + 8);
    acc = MFMA16(ahi, bhi, acc);
    acc = MFMA16(ahi, blo, acc);
    acc = MFMA16(alo, bhi, acc);
  }
  __syncthreads();                       // S1: h dead (u16 reads done; float writes follow)
  float* hfF = (float*)hfU;
  if (ks == 1) {
#pragma unroll
    for (int r = 0; r < 16; ++r) {
      const int rr = (r & 3) + 8 * (r >> 2) + 4 * lh;
      hfF[gb * 1088 + rr * 34 + l31] = acc[r];
    }
  }
  __syncthreads();                       // S2
  if (ks == 0) {
#pragma unroll
    for (int r = 0; r < 16; ++r) {
      const int rr = (r & 3) + 8 * (r >> 2) + 4 * lh;
      const float g = acc[r] + hfF[gb * 1088 + rr * 34 + l31];
      hfF[8192 + (gi * 32 + rr) * 66 + gj * 32 + l31] = g;   // final G, disjoint from scratch
    }
  }
  __syncthreads();                       // S3
  {
    const int i = tid >> 3, jt = tid & 7;
    const float gii = hfF[8192 + i * 66 + i];
    float dmin = 3.4e38f;
#pragma unroll
    for (int jj = 0; jj < 8; ++jj) {
      const int j = jt * 8 + jj;
      const float gjj = hfF[8192 + j * 66 + j];
      const float gij = hfF[8192 + i * 66 + j];
      float d2 = fmaxf(gii + gjj - 2.f * gij, 0.f);
      if (j == i) d2 += 1e9f;
      dmin = fminf(dmin, d2);
    }
    dmin = fminf(dmin, __shfl_xor(dmin, 1));
    dmin = fminf(dmin, __shfl_xor(dmin, 2));
    dmin = fminf(dmin, __shfl_xor(dmin, 4));
    if (jt == 0) mindS[i] = dmin;
  }
  __syncthreads();                       // S4: float G reads done before later u16 writes
}

// ---------------- small kernels ----------------
__global__ void zero_kernel(float* __restrict__ p, int n) {
  const int i = blockIdx.x * 256 + threadIdx.x;
  if (i < n) p[i] = 0.f;
}

__global__ void build_adj_kernel(const int* __restrict__ esrc, const int* __restrict__ edst,
                                 float* __restrict__ AdjF) {
  const int e = blockIdx.x * 256 + threadIdx.x;
  if (e < E_) {
    const int s = esrc[e];
    const int d = edst[e];
    const int g = s >> 6;
    atomicAdd(AdjF + g * 4096 + (d & 63) * 64 + (s & 63), 1.0f);
  }
}

__global__ __launch_bounds__(256) void enc_kernel(const float* __restrict__ x, const float* __restrict__ Wenc,
                                                  const float* __restrict__ benc, float* __restrict__ h0g) {
  __shared__ float xs[DF_];
  const int n = blockIdx.x;
  const int d = threadIdx.x;
  if (d < DF_) xs[d] = x[n * DF_ + d];
  __syncthreads();
  float acc = benc[d];
#pragma unroll
  for (int k = 0; k < DF_; ++k) acc = fmaf(xs[k], Wenc[k * D_ + d], acc);
  h0g[n * D_ + d] = fmaxf(acc, 0.f);
}

// Pre-split W (f16 hi/lo): off = (k>>3)*2048 + col*8 + (k&7); lo plane at +65536.
__global__ __launch_bounds__(256) void prep_wt(const float* __restrict__ gW1, const float* __restrict__ gW2,
                                               const float* __restrict__ Wn2n, u16* __restrict__ WTbuf) {
  const int mat = blockIdx.x;
  const float* Wsrc = (mat < 5) ? (gW1 + mat * 65536)
                    : (mat < 10) ? (gW2 + (mat - 5) * 65536) : Wn2n;
  u16* dst = WTbuf + (size_t)mat * 131072;
  for (int idx = threadIdx.x; idx < 65536; idx += 256) {
    const int k = idx >> 8, d = idx & 255;
    const float a = Wsrc[idx];
    u16 hi, lo; split_f16(a, hi, lo);
    const int off = (k >> 3) * 2048 + d * 8 + (k & 7);
    dst[off] = hi;
    dst[65536 + off] = lo;
  }
}

// ---------------- fused per-graph pipeline ----------------
__global__ __launch_bounds__(512, 4)
void mega_kernel(const float* __restrict__ h0g, const float* __restrict__ AdjF,
                 const u16* __restrict__ WTbuf,
                 const float* __restrict__ gb1, const float* __restrict__ gb2,
                 const float* __restrict__ eps, const float* __restrict__ aemb,
                 const float* __restrict__ bn2n,
                 const float* __restrict__ Wpred, const float* __restrict__ bpred,
                 float* __restrict__ outp) {
  __shared__ __align__(16) u16 hfU[64 * HROW];   // 66560 B split-h (also scratch when dead)
  __shared__ __align__(16) u16 AdjU[64 * 72];    //  9216 B f16 adjacency counts
  __shared__ float mindS[64];
  __shared__ float scoreS[64];
  __shared__ float hgS[256];
  __shared__ int   anchorS[64];

  const int tid = threadIdx.x;
  const int b = blockIdx.x;
  const int m = blockIdx.y;

  // stage adjacency (exact small ints -> f16)
  {
    const float* src = AdjF + b * 4096;
    for (int t = tid; t < 4096; t += 512)
      AdjU[(t >> 6) * 72 + (t & 63)] = h_bits((f16)src[t]);
  }
  if (tid < 64) anchorS[tid] = 0;
  // initial xcur = tx (split-write, vectorized b128 stores)
  {
    const int i = tid >> 3, part = tid & 7;
    const float* src = h0g + (b * 64 + i) * 256;
#pragma unroll
    for (int c = 0; c < 4; ++c) {
      const int chunk = part * 4 + c;
      const float4 v0 = *(const float4*)(src + chunk * 8);
      const float4 v1 = *(const float4*)(src + chunk * 8 + 4);
      const float vv[8] = {v0.x, v0.y, v0.z, v0.w, v1.x, v1.y, v1.z, v1.w};
      f16x8 hi8, lo8;
#pragma unroll
      for (int e = 0; e < 8; ++e) { u16 h, l; split_f16(vv[e], h, l); hi8[e] = bits_h(h); lo8[e] = bits_h(l); }
      const int a = haddr8(i, chunk);
      *(f16x8*)(hfU + a) = hi8;
      *(f16x8*)(hfU + a + 8) = lo8;
    }
  }
  __syncthreads();

  for (int iter = 1; iter <= NA_ + 1; ++iter) {
    for (int l = 0; l < L_; ++l) {
      const float epsl = 1.0f + eps[l];
      gemm_adj_mfma(hfU, AdjU, epsl);
      gemm_w_mfma(hfU, WTbuf + (size_t)l * 131072,       gb1 + l * D_, true);
      gemm_w_mfma(hfU, WTbuf + (size_t)(5 + l) * 131072, gb2 + l * D_, true);
    }
    if (iter == NA_ + 1) break;

    mindist_mfma(hfU, mindS);

    // ----- Gumbel-argmax sampling (exact JAX threefry) -----
    if (tid < 64) {
      const int j = tid;
      uint32_t k0, k1;
      threefry2x32(0u, 42u, 0u, (uint32_t)iter, k0, k1);
      const uint32_t p = (uint32_t)(m * (B_ * NPG_) + b * NPG_ + j);
      uint32_t o0, o1, bits;
      if (p < 32768u) { threefry2x32(k0, k1, p, p + 32768u, o0, o1); bits = o0; }
      else            { threefry2x32(k0, k1, p - 32768u, p, o0, o1); bits = o1; }
      const float f = __uint_as_float((bits >> 9) | 0x3f800000u) - 1.0f;
      const float uv = fmaxf(1e-9f, f + 1e-9f);
      const float pred = -mindS[j] - ((anchorS[j] > 0) ? 10.0f : 0.0f);
      scoreS[j] = pred - logf(-logf(uv));
    }
    __syncthreads();
    if (tid == 0) {
      int best = 0; float bv = scoreS[0];
      for (int j = 1; j < 64; ++j) { const float v = scoreS[j]; if (v > bv) { bv = v; best = j; } }
      anchorS[best] = iter;
    }
    __syncthreads();
    // ----- xcur = tx * anchor_emb[anchor] + tx (split-write) -----
    {
      const int i = tid >> 3, part = tid & 7;
      const float* t = h0g + (b * 64 + i) * 256;
      const float* e = aemb + anchorS[i] * D_;
#pragma unroll
      for (int c = 0; c < 4; ++c) {
        const int chunk = part * 4 + c;
        const float4 tv0 = *(const float4*)(t + chunk * 8);
        const float4 tv1 = *(const float4*)(t + chunk * 8 + 4);
        const float4 ev0 = *(const float4*)(e + chunk * 8);
        const float4 ev1 = *(const float4*)(e + chunk * 8 + 4);
        float vv[8];
        vv[0] = fmaf(tv0.x, ev0.x, tv0.x); vv[1] = fmaf(tv0.y, ev0.y, tv0.y);
        vv[2] = fmaf(tv0.z, ev0.z, tv0.z); vv[3] = fmaf(tv0.w, ev0.w, tv0.w);
        vv[4] = fmaf(tv1.x, ev1.x, tv1.x); vv[5] = fmaf(tv1.y, ev1.y, tv1.y);
        vv[6] = fmaf(tv1.z, ev1.z, tv1.z); vv[7] = fmaf(tv1.w, ev1.w, tv1.w);
        f16x8 hi8, lo8;
#pragma unroll
        for (int ee = 0; ee < 8; ++ee) { u16 h, l; split_f16(vv[ee], h, l); hi8[ee] = bits_h(h); lo8[ee] = bits_h(l); }
        const int a = haddr8(i, chunk);
        *(f16x8*)(hfU + a) = hi8;
        *(f16x8*)(hfU + a + 8) = lo8;
      }
    }
    __syncthreads();
  }

  // ----- head: hn = relu(h @ W_n2n + b_n2n) in-place, then graph mean + pred -----
  gemm_w_mfma(hfU, WTbuf + (size_t)10 * 131072, bn2n, true);
  if (tid < 256) {
    const int dc = tid >> 3, de = tid & 7;
    float s = 0.f;
    for (int i = 0; i < 64; ++i) {
      const int ad = i * HROW + ((dc ^ (i & 7)) << 4) + de;
      s += h2f(hfU[ad]) + h2f(hfU[ad + 8]);
    }
    hgS[tid] = s * (1.0f / 64.0f);
  }
  __syncthreads();
  if (tid < 160) {
    const int t = tid >> 4, part = tid & 15;
    float s = 0.f;
    for (int d = part * 16; d < part * 16 + 16; ++d) s = fmaf(hgS[d], Wpred[d * TASKS_ + t], s);
    s += __shfl_xor(s, 1); s += __shfl_xor(s, 2); s += __shfl_xor(s, 4); s += __shfl_xor(s, 8);
    if (part == 0) {
      float val = s * 0.25f;
      if (m == 0) val += bpred[t];
      atomicAdd(outp + b * TASKS_ + t, val);
    }
  }
}

// ---------------- launch ----------------
extern "C" void kernel_launch(void* const* d_in, const int* in_sizes, int n_in,
                              void* d_out, int out_size, void* d_ws, size_t ws_size,
                              hipStream_t stream) {
  const float* x     = (const float*)d_in[0];
  const float* Wenc  = (const float*)d_in[1];
  const float* benc  = (const float*)d_in[2];
  const float* gW1   = (const float*)d_in[3];
  const float* gb1   = (const float*)d_in[4];
  const float* gW2   = (const float*)d_in[5];
  const float* gb2   = (const float*)d_in[6];
  const float* eps   = (const float*)d_in[7];
  const float* aemb  = (const float*)d_in[8];
  const float* Wn2n  = (const float*)d_in[9];
  const float* bn2n  = (const float*)d_in[10];
  const float* Wpred = (const float*)d_in[11];
  const float* bpred = (const float*)d_in[12];
  const int* esrc    = (const int*)d_in[13];
  const int* edst    = (const int*)d_in[14];
  float* outp = (float*)d_out;

  float* h0g  = (float*)d_ws;                      // 16 MB
  float* AdjF = h0g + (size_t)N_ * D_;             // 4 MB
  u16* WTbuf  = (u16*)(AdjF + B_ * 4096);          // 11 * 256 KB f16 split weights

  zero_kernel<<<dim3((B_ * 4096 + 255) / 256), dim3(256), 0, stream>>>(AdjF, B_ * 4096);
  zero_kernel<<<dim3((out_size + 255) / 256), dim3(256), 0, stream>>>(outp, out_size);
  build_adj_kernel<<<dim3((E_ + 255) / 256), dim3(256), 0, stream>>>(esrc, edst, AdjF);
  enc_kernel<<<dim3(N_), dim3(256), 0, stream>>>(x, Wenc, benc, h0g);
  prep_wt<<<dim3(11), dim3(256), 0, stream>>>(gW1, gW2, Wn2n, WTbuf);
  mega_kernel<<<dim3(B_, M_), dim3(512), 0, stream>>>(h0g, AdjF, WTbuf, gb1, gb2,
                                                      eps, aemb, bn2n, Wpred, bpred, outp);
}

// Round 6
// 799.831 us; speedup vs baseline: 5.5831x; 1.4324x over previous
//
#include <hip/hip_runtime.h>
#include <stdint.h>

typedef unsigned short u16;
typedef _Float16 f16;
typedef f16 f16x8 __attribute__((ext_vector_type(8)));
typedef float f32x16 __attribute__((ext_vector_type(16)));

// Problem constants
#define M_     4
#define B_     256
#define NPG_   64
#define N_     (B_*NPG_)    // 16384
#define DEG_   8
#define E_     (N_*DEG_)    // 131072
#define DF_    16
#define D_     256
#define L_     5
#define NA_    2
#define TASKS_ 10

#define HROW 520            // u16 row stride of split-h buffer (1040 B, 16B aligned)
#define MFMA16(a,b,c) __builtin_amdgcn_mfma_f32_32x32x16_f16(a,b,c,0,0,0)

// ---------------- f16 helpers ----------------
__device__ __forceinline__ u16 h_bits(f16 h) { union { f16 h; u16 u; } c; c.h = h; return c.u; }
__device__ __forceinline__ f16 bits_h(u16 u) { union { u16 u; f16 h; } c; c.u = u; return c.h; }
__device__ __forceinline__ float h2f(u16 u) { return (float)bits_h(u); }
__device__ __forceinline__ void split_f16(float v, u16& hi, u16& lo) {
  f16 h = (f16)v;
  f16 l = (f16)(v - (float)h);
  hi = h_bits(h); lo = h_bits(l);
}

// u16 index of the 8-elem hi group for (row, chunk); lo group at +8. XOR swizzle on chunk.
__device__ __forceinline__ int haddr8(int row, int chunk) {
  return row * HROW + ((chunk ^ (row & 7)) << 4);
}
__device__ __forceinline__ void write_split(u16* hfU, int row, int col, float v) {
  const int ad = haddr8(row, col >> 3) + (col & 7);
  u16 hi, lo; split_f16(v, hi, lo);
  hfU[ad] = hi; hfU[ad + 8] = lo;
}

// ---------------- Threefry-2x32 (exact JAX semantics) ----------------
__device__ __forceinline__ uint32_t rotl32(uint32_t v, int r) { return (v << r) | (v >> (32 - r)); }
__device__ __forceinline__ void threefry2x32(uint32_t k0, uint32_t k1, uint32_t x0, uint32_t x1,
                                             uint32_t& o0, uint32_t& o1) {
  const uint32_t ks2 = k0 ^ k1 ^ 0x1BD11BDAu;
  x0 += k0; x1 += k1;
#define TFR(r) { x0 += x1; x1 = rotl32(x1, r); x1 ^= x0; }
  TFR(13) TFR(15) TFR(26) TFR(6)   x0 += k1;  x1 += ks2 + 1u;
  TFR(17) TFR(29) TFR(16) TFR(24)  x0 += ks2; x1 += k0 + 2u;
  TFR(13) TFR(15) TFR(26) TFR(6)   x0 += k0;  x1 += k1 + 3u;
  TFR(17) TFR(29) TFR(16) TFR(24)  x0 += k1;  x1 += ks2 + 4u;
  TFR(13) TFR(15) TFR(26) TFR(6)   x0 += ks2; x1 += k0 + 5u;
#undef TFR
  o0 = x0; o1 = x1;
}

// ---------------- MFMA gemm: h = relu?(h @ W + b), in-place on split-h ----------------
// Wave w owns col-block w (cols 32w..32w+31) for BOTH row-blocks; full K.
// WTm layout (u16): off = hilo*65536 + (k>>3)*2048 + col*8 + (k&7).
// TERMS=3: ahi*(bh+bl)+alo*bh (split precision). TERMS=1: ahi*bh only (output path).
template<int TERMS>
__device__ __forceinline__ void gemm_w_mfma(u16* __restrict__ hfU, const u16* __restrict__ WTm,
                                            const float* __restrict__ bias, bool do_relu) {
  const int tid = threadIdx.x;
  const int lane = tid & 63, w = tid >> 6;
  const int l31 = lane & 31, lh = lane >> 5;
  const int col = w * 32 + l31;
  const float bv = bias[col];

  f32x16 acc0 = {}, acc1 = {};
  const u16* Bbase = WTm + col * 8;
#pragma unroll
  for (int ks = 0; ks < 16; ++ks) {
    const int chunk = ks * 2 + lh;                 // k = 8*chunk + e
    const int a0 = haddr8(l31, chunk);
    const int a1 = haddr8(32 + l31, chunk);
    const f16x8 ahi0 = *(const f16x8*)(hfU + a0);
    const f16x8 ahi1 = *(const f16x8*)(hfU + a1);
    const f16x8 bh = *(const f16x8*)(Bbase + chunk * 2048);
    if (TERMS == 3) {
      const f16x8 alo0 = *(const f16x8*)(hfU + a0 + 8);
      const f16x8 alo1 = *(const f16x8*)(hfU + a1 + 8);
      const f16x8 bl = *(const f16x8*)(Bbase + chunk * 2048 + 65536);
      acc0 = MFMA16(ahi0, bh, acc0);
      acc0 = MFMA16(ahi0, bl, acc0);
      acc0 = MFMA16(alo0, bh, acc0);
      acc1 = MFMA16(ahi1, bh, acc1);
      acc1 = MFMA16(ahi1, bl, acc1);
      acc1 = MFMA16(alo1, bh, acc1);
    } else {
      acc0 = MFMA16(ahi0, bh, acc0);
      acc1 = MFMA16(ahi1, bh, acc1);
    }
  }
  __syncthreads();                       // S1: all A reads done, h region dead
#pragma unroll
  for (int r = 0; r < 16; ++r) {
    const int rr = (r & 3) + 8 * (r >> 2) + 4 * lh;
    float v0 = acc0[r] + bv;
    float v1 = acc1[r] + bv;
    if (do_relu) { v0 = fmaxf(v0, 0.f); v1 = fmaxf(v1, 0.f); }
    write_split(hfU, rr, col, v0);       // rows 0..31
    write_split(hfU, 32 + rr, col, v1);  // rows 32..63
  }
  __syncthreads();                       // S2: new h ready
}

// ---------------- GIN aggregation via MFMA: h = Adj@h + (1+eps)h, in-place ----------------
template<int TERMS>
__device__ __forceinline__ void gemm_adj_mfma(u16* __restrict__ hfU, const u16* __restrict__ AdjU,
                                              float epsl) {
  const int tid = threadIdx.x;
  const int lane = tid & 63, w = tid >> 6;
  const int l31 = lane & 31, lh = lane >> 5;
  const int d = w * 32 + l31;
  const int dc = d >> 3, de = d & 7;
  f32x16 acc0 = {}, acc1 = {};
#pragma unroll
  for (int kk = 0; kk < 4; ++kk) {
    const f16x8 A0 = *(const f16x8*)(AdjU + l31 * 72 + (kk * 2 + lh) * 8);
    const f16x8 A1 = *(const f16x8*)(AdjU + (32 + l31) * 72 + (kk * 2 + lh) * 8);
    const int jb = kk * 16 + lh * 8;
    f16x8 bh, bl;
#pragma unroll
    for (int jj = 0; jj < 8; ++jj) {
      const int j = jb + jj;
      const int ad = j * HROW + (((dc) ^ (j & 7)) << 4) + de;
      bh[jj] = bits_h(hfU[ad]);
      if (TERMS == 3) bl[jj] = bits_h(hfU[ad + 8]);
    }
    acc0 = MFMA16(A0, bh, acc0);
    acc1 = MFMA16(A1, bh, acc1);
    if (TERMS == 3) {
      acc0 = MFMA16(A0, bl, acc0);
      acc1 = MFMA16(A1, bl, acc1);
    }
  }
  // self term (1+eps)*h, read before h is overwritten
  float self0[16], self1[16];
#pragma unroll
  for (int r = 0; r < 16; ++r) {
    const int rr = (r & 3) + 8 * (r >> 2) + 4 * lh;
    { const int ad = rr * HROW + ((dc ^ (rr & 7)) << 4) + de;
      self0[r] = h2f(hfU[ad]) + h2f(hfU[ad + 8]); }
    { const int r1 = 32 + rr; const int ad = r1 * HROW + ((dc ^ (r1 & 7)) << 4) + de;
      self1[r] = h2f(hfU[ad]) + h2f(hfU[ad + 8]); }
  }
  __syncthreads();                       // S1: all reads done
#pragma unroll
  for (int r = 0; r < 16; ++r) {
    const int rr = (r & 3) + 8 * (r >> 2) + 4 * lh;
    write_split(hfU, rr, d, acc0[r] + epsl * self0[r]);
    write_split(hfU, 32 + rr, d, acc1[r] + epsl * self1[r]);
  }
  __syncthreads();                       // S2
}

// ---------------- mindist via Gram matrix G = h h^T (MFMA), h dead afterwards ----------------
__device__ __forceinline__ void mindist_mfma(u16* __restrict__ hfU, float* __restrict__ mindS) {
  const int tid = threadIdx.x;
  const int lane = tid & 63, w = tid >> 6;
  const int gb = w & 3, gi = gb >> 1, gj = gb & 1, ks = w >> 2;
  const int l31 = lane & 31, lh = lane >> 5;
  f32x16 acc = {};
#pragma unroll
  for (int t = 0; t < 8; ++t) {
    const int chunk = 4 * t + 2 * ks + lh;
    const int ra = haddr8(gi * 32 + l31, chunk);
    const int rb_ = haddr8(gj * 32 + l31, chunk);
    const f16x8 ahi = *(const f16x8*)(hfU + ra);
    const f16x8 alo = *(const f16x8*)(hfU + ra + 8);
    const f16x8 bhi = *(const f16x8*)(hfU + rb_);
    const f16x8 blo = *(const f16x8*)(hfU + rb_ + 8);
    acc = MFMA16(ahi, bhi, acc);
    acc = MFMA16(ahi, blo, acc);
    acc = MFMA16(alo, bhi, acc);
  }
  __syncthreads();                       // S1: h dead
  float* hfF = (float*)hfU;
  if (ks == 1) {
#pragma unroll
    for (int r = 0; r < 16; ++r) {
      const int rr = (r & 3) + 8 * (r >> 2) + 4 * lh;
      hfF[gb * 1088 + rr * 34 + l31] = acc[r];
    }
  }
  __syncthreads();                       // S2
  if (ks == 0) {
#pragma unroll
    for (int r = 0; r < 16; ++r) {
      const int rr = (r & 3) + 8 * (r >> 2) + 4 * lh;
      const float g = acc[r] + hfF[gb * 1088 + rr * 34 + l31];
      hfF[8192 + (gi * 32 + rr) * 66 + gj * 32 + l31] = g;
    }
  }
  __syncthreads();                       // S3
  {
    const int i = tid >> 3, jt = tid & 7;
    const float gii = hfF[8192 + i * 66 + i];
    float dmin = 3.4e38f;
#pragma unroll
    for (int jj = 0; jj < 8; ++jj) {
      const int j = jt * 8 + jj;
      const float gjj = hfF[8192 + j * 66 + j];
      const float gij = hfF[8192 + i * 66 + j];
      float d2 = fmaxf(gii + gjj - 2.f * gij, 0.f);
      if (j == i) d2 += 1e9f;
      dmin = fminf(dmin, d2);
    }
    dmin = fminf(dmin, __shfl_xor(dmin, 1));
    dmin = fminf(dmin, __shfl_xor(dmin, 2));
    dmin = fminf(dmin, __shfl_xor(dmin, 4));
    if (jt == 0) mindS[i] = dmin;
  }
  __syncthreads();                       // S4
}

// ---------------- shared staging helpers ----------------
__device__ __forceinline__ void stage_adj(u16* AdjU, const float* AdjF, int b, int tid) {
  const float* src = AdjF + b * 4096;
  for (int t = tid; t < 4096; t += 512)
    AdjU[(t >> 6) * 72 + (t & 63)] = h_bits((f16)src[t]);
}

__device__ __forceinline__ void stage_h0(u16* hfU, const float* h0g, int b, int tid) {
  const int i = tid >> 3, part = tid & 7;
  const float* src = h0g + (b * 64 + i) * 256;
#pragma unroll
  for (int c = 0; c < 4; ++c) {
    const int chunk = part * 4 + c;
    const float4 v0 = *(const float4*)(src + chunk * 8);
    const float4 v1 = *(const float4*)(src + chunk * 8 + 4);
    const float vv[8] = {v0.x, v0.y, v0.z, v0.w, v1.x, v1.y, v1.z, v1.w};
    f16x8 hi8, lo8;
#pragma unroll
    for (int e = 0; e < 8; ++e) { u16 h, l; split_f16(vv[e], h, l); hi8[e] = bits_h(h); lo8[e] = bits_h(l); }
    const int a = haddr8(i, chunk);
    *(f16x8*)(hfU + a) = hi8;
    *(f16x8*)(hfU + a + 8) = lo8;
  }
}

// xcur = tx * anchor_emb[anchor] + tx (split-write)
__device__ __forceinline__ void build_xcur(u16* hfU, const float* h0g, const float* aemb,
                                           const int* anchorS, int b, int tid) {
  const int i = tid >> 3, part = tid & 7;
  const float* t = h0g + (b * 64 + i) * 256;
  const float* e = aemb + anchorS[i] * D_;
#pragma unroll
  for (int c = 0; c < 4; ++c) {
    const int chunk = part * 4 + c;
    const float4 tv0 = *(const float4*)(t + chunk * 8);
    const float4 tv1 = *(const float4*)(t + chunk * 8 + 4);
    const float4 ev0 = *(const float4*)(e + chunk * 8);
    const float4 ev1 = *(const float4*)(e + chunk * 8 + 4);
    float vv[8];
    vv[0] = fmaf(tv0.x, ev0.x, tv0.x); vv[1] = fmaf(tv0.y, ev0.y, tv0.y);
    vv[2] = fmaf(tv0.z, ev0.z, tv0.z); vv[3] = fmaf(tv0.w, ev0.w, tv0.w);
    vv[4] = fmaf(tv1.x, ev1.x, tv1.x); vv[5] = fmaf(tv1.y, ev1.y, tv1.y);
    vv[6] = fmaf(tv1.z, ev1.z, tv1.z); vv[7] = fmaf(tv1.w, ev1.w, tv1.w);
    f16x8 hi8, lo8;
#pragma unroll
    for (int ee = 0; ee < 8; ++ee) { u16 h, l; split_f16(vv[ee], h, l); hi8[ee] = bits_h(h); lo8[ee] = bits_h(l); }
    const int a = haddr8(i, chunk);
    *(f16x8*)(hfU + a) = hi8;
    *(f16x8*)(hfU + a + 8) = lo8;
  }
}

// Gumbel-argmax sampling (exact JAX threefry); updates anchorS. Call with all threads; sync outside.
__device__ __forceinline__ void sample_anchor(const float* mindS, float* scoreS, int* anchorS,
                                              int m, int b, int iter, int tid) {
  if (tid < 64) {
    const int j = tid;
    uint32_t k0, k1;
    threefry2x32(0u, 42u, 0u, (uint32_t)iter, k0, k1);
    const uint32_t p = (uint32_t)(m * (B_ * NPG_) + b * NPG_ + j);
    uint32_t o0, o1, bits;
    if (p < 32768u) { threefry2x32(k0, k1, p, p + 32768u, o0, o1); bits = o0; }
    else            { threefry2x32(k0, k1, p - 32768u, p, o0, o1); bits = o1; }
    const float f = __uint_as_float((bits >> 9) | 0x3f800000u) - 1.0f;
    const float uv = fmaxf(1e-9f, f + 1e-9f);
    const float pred = -mindS[j] - ((anchorS[j] > 0) ? 10.0f : 0.0f);
    scoreS[j] = pred - logf(-logf(uv));
  }
  __syncthreads();
  if (tid == 0) {
    int best = 0; float bv = scoreS[0];
    for (int j = 1; j < 64; ++j) { const float v = scoreS[j]; if (v > bv) { bv = v; best = j; } }
    anchorS[best] = iter;
  }
}

// ---------------- small kernels ----------------
__global__ void zero_kernel(float* __restrict__ p, int n) {
  const int i = blockIdx.x * 256 + threadIdx.x;
  if (i < n) p[i] = 0.f;
}

__global__ void build_adj_kernel(const int* __restrict__ esrc, const int* __restrict__ edst,
                                 float* __restrict__ AdjF) {
  const int e = blockIdx.x * 256 + threadIdx.x;
  if (e < E_) {
    const int s = esrc[e];
    const int d = edst[e];
    const int g = s >> 6;
    atomicAdd(AdjF + g * 4096 + (d & 63) * 64 + (s & 63), 1.0f);
  }
}

__global__ __launch_bounds__(256) void enc_kernel(const float* __restrict__ x, const float* __restrict__ Wenc,
                                                  const float* __restrict__ benc, float* __restrict__ h0g) {
  __shared__ float xs[DF_];
  const int n = blockIdx.x;
  const int d = threadIdx.x;
  if (d < DF_) xs[d] = x[n * DF_ + d];
  __syncthreads();
  float acc = benc[d];
#pragma unroll
  for (int k = 0; k < DF_; ++k) acc = fmaf(xs[k], Wenc[k * D_ + d], acc);
  h0g[n * D_ + d] = fmaxf(acc, 0.f);
}

// Pre-split W (f16 hi/lo): off = (k>>3)*2048 + col*8 + (k&7); lo plane at +65536.
__global__ __launch_bounds__(256) void prep_wt(const float* __restrict__ gW1, const float* __restrict__ gW2,
                                               const float* __restrict__ Wn2n, u16* __restrict__ WTbuf) {
  const int mat = blockIdx.x;
  const float* Wsrc = (mat < 5) ? (gW1 + mat * 65536)
                    : (mat < 10) ? (gW2 + (mat - 5) * 65536) : Wn2n;
  u16* dst = WTbuf + (size_t)mat * 131072;
  for (int idx = threadIdx.x; idx < 65536; idx += 256) {
    const int k = idx >> 8, d = idx & 255;
    const float a = Wsrc[idx];
    u16 hi, lo; split_f16(a, hi, lo);
    const int off = (k >> 3) * 2048 + d * 8 + (k & 7);
    dst[off] = hi;
    dst[65536 + off] = lo;
  }
}

// ---------------- phase 1: iter-1 GNN + mindist, m-invariant -> once per b ----------------
__global__ __launch_bounds__(512)
void gnn1_kernel(const float* __restrict__ h0g, const float* __restrict__ AdjF,
                 const u16* __restrict__ WTbuf,
                 const float* __restrict__ gb1, const float* __restrict__ gb2,
                 const float* __restrict__ eps, float* __restrict__ mindG) {
  __shared__ __align__(16) u16 hfU[64 * HROW];
  __shared__ __align__(16) u16 AdjU[64 * 72];
  __shared__ float mindS[64];
  const int tid = threadIdx.x;
  const int b = blockIdx.x;

  stage_adj(AdjU, AdjF, b, tid);
  stage_h0(hfU, h0g, b, tid);
  __syncthreads();

  for (int l = 0; l < L_; ++l) {
    const float epsl = 1.0f + eps[l];
    gemm_adj_mfma<3>(hfU, AdjU, epsl);
    gemm_w_mfma<3>(hfU, WTbuf + (size_t)l * 131072,       gb1 + l * D_, true);
    gemm_w_mfma<3>(hfU, WTbuf + (size_t)(5 + l) * 131072, gb2 + l * D_, true);
  }
  mindist_mfma(hfU, mindS);
  if (tid < 64) mindG[b * 64 + tid] = mindS[tid];
}

// ---------------- phase 2: per (b,m) — sample a1, iters 2..3, head ----------------
__global__ __launch_bounds__(512, 4)
void mega_kernel(const float* __restrict__ h0g, const float* __restrict__ AdjF,
                 const u16* __restrict__ WTbuf,
                 const float* __restrict__ gb1, const float* __restrict__ gb2,
                 const float* __restrict__ eps, const float* __restrict__ aemb,
                 const float* __restrict__ bn2n,
                 const float* __restrict__ Wpred, const float* __restrict__ bpred,
                 const float* __restrict__ mindG, float* __restrict__ outp) {
  __shared__ __align__(16) u16 hfU[64 * HROW];   // 66560 B split-h (also scratch when dead)
  __shared__ __align__(16) u16 AdjU[64 * 72];    //  9216 B f16 adjacency counts
  __shared__ float mindS[64];
  __shared__ float scoreS[64];
  __shared__ float hgS[256];
  __shared__ int   anchorS[64];

  const int tid = threadIdx.x;
  const int b = blockIdx.x;
  const int m = blockIdx.y;

  stage_adj(AdjU, AdjF, b, tid);
  if (tid < 64) { anchorS[tid] = 0; mindS[tid] = mindG[b * 64 + tid]; }
  __syncthreads();

  // iter-1 sampling from precomputed mindist
  sample_anchor(mindS, scoreS, anchorS, m, b, 1, tid);
  __syncthreads();
  build_xcur(hfU, h0g, aemb, anchorS, b, tid);
  __syncthreads();

  // ----- iter 2: full-precision GNN (feeds argmax) -----
  for (int l = 0; l < L_; ++l) {
    const float epsl = 1.0f + eps[l];
    gemm_adj_mfma<3>(hfU, AdjU, epsl);
    gemm_w_mfma<3>(hfU, WTbuf + (size_t)l * 131072,       gb1 + l * D_, true);
    gemm_w_mfma<3>(hfU, WTbuf + (size_t)(5 + l) * 131072, gb2 + l * D_, true);
  }
  mindist_mfma(hfU, mindS);
  sample_anchor(mindS, scoreS, anchorS, m, b, 2, tid);
  __syncthreads();
  build_xcur(hfU, h0g, aemb, anchorS, b, tid);
  __syncthreads();

  // ----- iter 3: output-path GNN, 1-term f16 (tolerance is bf16-scale) -----
  for (int l = 0; l < L_; ++l) {
    const float epsl = 1.0f + eps[l];
    gemm_adj_mfma<1>(hfU, AdjU, epsl);
    gemm_w_mfma<1>(hfU, WTbuf + (size_t)l * 131072,       gb1 + l * D_, true);
    gemm_w_mfma<1>(hfU, WTbuf + (size_t)(5 + l) * 131072, gb2 + l * D_, true);
  }

  // ----- head: hn = relu(h @ W_n2n + b_n2n) (1-term), graph mean, pred -----
  gemm_w_mfma<1>(hfU, WTbuf + (size_t)10 * 131072, bn2n, true);
  if (tid < 256) {
    const int dc = tid >> 3, de = tid & 7;
    float s = 0.f;
    for (int i = 0; i < 64; ++i) {
      const int ad = i * HROW + ((dc ^ (i & 7)) << 4) + de;
      s += h2f(hfU[ad]) + h2f(hfU[ad + 8]);
    }
    hgS[tid] = s * (1.0f / 64.0f);
  }
  __syncthreads();
  if (tid < 160) {
    const int t = tid >> 4, part = tid & 15;
    float s = 0.f;
    for (int d = part * 16; d < part * 16 + 16; ++d) s = fmaf(hgS[d], Wpred[d * TASKS_ + t], s);
    s += __shfl_xor(s, 1); s += __shfl_xor(s, 2); s += __shfl_xor(s, 4); s += __shfl_xor(s, 8);
    if (part == 0) {
      float val = s * 0.25f;
      if (m == 0) val += bpred[t];
      atomicAdd(outp + b * TASKS_ + t, val);
    }
  }
}

// ---------------- launch ----------------
extern "C" void kernel_launch(void* const* d_in, const int* in_sizes, int n_in,
                              void* d_out, int out_size, void* d_ws, size_t ws_size,
                              hipStream_t stream) {
  const float* x     = (const float*)d_in[0];
  const float* Wenc  = (const float*)d_in[1];
  const float* benc  = (const float*)d_in[2];
  const float* gW1   = (const float*)d_in[3];
  const float* gb1   = (const float*)d_in[4];
  const float* gW2   = (const float*)d_in[5];
  const float* gb2   = (const float*)d_in[6];
  const float* eps   = (const float*)d_in[7];
  const float* aemb  = (const float*)d_in[8];
  const float* Wn2n  = (const float*)d_in[9];
  const float* bn2n  = (const float*)d_in[10];
  const float* Wpred = (const float*)d_in[11];
  const float* bpred = (const float*)d_in[12];
  const int* esrc    = (const int*)d_in[13];
  const int* edst    = (const int*)d_in[14];
  float* outp = (float*)d_out;

  float* h0g  = (float*)d_ws;                      // 16 MB
  float* AdjF = h0g + (size_t)N_ * D_;             // 4 MB
  u16* WTbuf  = (u16*)(AdjF + B_ * 4096);          // 11 * 256 KB f16 split weights
  float* mindG = (float*)(WTbuf + (size_t)11 * 131072);   // B*64 floats

  zero_kernel<<<dim3((B_ * 4096 + 255) / 256), dim3(256), 0, stream>>>(AdjF, B_ * 4096);
  zero_kernel<<<dim3((out_size + 255) / 256), dim3(256), 0, stream>>>(outp, out_size);
  build_adj_kernel<<<dim3((E_ + 255) / 256), dim3(256), 0, stream>>>(esrc, edst, AdjF);
  enc_kernel<<<dim3(N_), dim3(256), 0, stream>>>(x, Wenc, benc, h0g);
  prep_wt<<<dim3(11), dim3(256), 0, stream>>>(gW1, gW2, Wn2n, WTbuf);
  gnn1_kernel<<<dim3(B_), dim3(512), 0, stream>>>(h0g, AdjF, WTbuf, gb1, gb2, eps, mindG);
  mega_kernel<<<dim3(B_, M_), dim3(512), 0, stream>>>(h0g, AdjF, WTbuf, gb1, gb2,
                                                      eps, aemb, bn2n, Wpred, bpred, mindG, outp);
}